// Round 1
// baseline (444.082 us; speedup 1.0000x reference)
//
#include <hip/hip_runtime.h>

#define DM 1024
#define ED 2048
#define LEN 2048
#define NB 2
#define NROWS (NB*LEN)   // 4096
#define DTR 64
#define NST 16
#define XDBL 96          // DTR + 2*NST
#define NCH 32
#define CHL 64           // LEN/NCH

typedef __attribute__((ext_vector_type(8))) __bf16 bf16x8;
typedef __attribute__((ext_vector_type(8))) short short8;
typedef __attribute__((ext_vector_type(4))) float f32x4;
typedef unsigned short u16;
typedef __attribute__((ext_vector_type(4))) unsigned short u16x4;

__device__ __forceinline__ u16 f2bf(float f){
  union { float f; unsigned int u; } v; v.f = f;
  unsigned int u = v.u;
  return (u16)((u + 0x7FFFu + ((u >> 16) & 1u)) >> 16);
}
__device__ __forceinline__ float bf2f(u16 h){
  union { unsigned int u; float f; } v; v.u = ((unsigned int)h) << 16; return v.f;
}

__global__ __launch_bounds__(256) void k_f2bf(const float* __restrict__ in, u16* __restrict__ out, int n){
  int i = blockIdx.x*256 + threadIdx.x;
  if (i < n) out[i] = f2bf(in[i]);
}

// -------- LayerNorm: one block per row of 1024 --------
__global__ __launch_bounds__(256) void k_ln(const float* __restrict__ x, const float* __restrict__ w,
                                            const float* __restrict__ b, u16* __restrict__ out){
  int row = blockIdx.x;
  const float4* xp = reinterpret_cast<const float4*>(x + (size_t)row*DM);
  float4 v = xp[threadIdx.x];
  float s  = v.x+v.y+v.z+v.w;
  float sq = v.x*v.x+v.y*v.y+v.z*v.z+v.w*v.w;
  #pragma unroll
  for (int off=32; off; off>>=1){ s += __shfl_xor(s, off); sq += __shfl_xor(sq, off); }
  __shared__ float red[8];
  int wid = threadIdx.x>>6, lane = threadIdx.x&63;
  if (!lane){ red[wid]=s; red[4+wid]=sq; }
  __syncthreads();
  s  = red[0]+red[1]+red[2]+red[3];
  sq = red[4]+red[5]+red[6]+red[7];
  float mean = s * (1.0f/DM);
  float var  = sq * (1.0f/DM) - mean*mean;
  float rstd = rsqrtf(var + 1e-5f);
  int c0 = threadIdx.x*4;
  float vals[4] = {v.x,v.y,v.z,v.w};
  u16x4 o;
  #pragma unroll
  for (int j=0;j<4;j++){
    int c = c0+j;
    o[j] = f2bf((vals[j]-mean)*rstd*w[c] + b[c]);
  }
  *reinterpret_cast<u16x4*>(out + (size_t)row*DM + c0) = o;
}

// -------- GEMM C[M,N] = A[M,K] * B[N,K]^T  (both row-major, bf16 in, f32 out) --------
// EPI: 0 plain, 1 softplus(acc + bias[n]), 2 acc + res[m*ldc+n]
template<int MI, int NI, int WVM, int WVN, int EPI>
__global__ __launch_bounds__(WVM*WVN*64) void k_gemm_bt(
    const u16* __restrict__ A, const u16* __restrict__ B,
    float* __restrict__ C, int M, int N, int K, int lda, int ldb, int ldc,
    const float* __restrict__ bias, const float* __restrict__ res)
{
  int lane = threadIdx.x & 63;
  int w    = threadIdx.x >> 6;
  int wm = w % WVM, wn = w / WVM;
  int bm = blockIdx.x * (WVM*MI*16);
  int bn = blockIdx.y * (WVN*NI*16);
  int r  = lane & 15;
  int ks = (lane >> 4) * 8;
  const u16* Ap = A + (size_t)(bm + wm*MI*16 + r)*lda + ks;
  const u16* Bp = B + (size_t)(bn + wn*NI*16 + r)*ldb + ks;
  f32x4 acc[MI][NI];
  #pragma unroll
  for (int i=0;i<MI;i++)
    #pragma unroll
    for(int j=0;j<NI;j++) acc[i][j] = (f32x4)0.f;

  for (int kk=0; kk<K; kk+=32){
    short8 a[MI], b[NI];
    #pragma unroll
    for (int i=0;i<MI;i++) a[i] = *reinterpret_cast<const short8*>(Ap + (size_t)i*16*lda + kk);
    #pragma unroll
    for (int j=0;j<NI;j++) b[j] = *reinterpret_cast<const short8*>(Bp + (size_t)j*16*ldb + kk);
    #pragma unroll
    for (int i=0;i<MI;i++)
      #pragma unroll
      for (int j=0;j<NI;j++)
        acc[i][j] = __builtin_amdgcn_mfma_f32_16x16x32_bf16(
            __builtin_bit_cast(bf16x8, a[i]), __builtin_bit_cast(bf16x8, b[j]), acc[i][j], 0,0,0);
  }
  int rowbase = bm + wm*MI*16 + (lane>>4)*4;
  int colbase = bn + wn*NI*16 + (lane&15);
  #pragma unroll
  for (int i=0;i<MI;i++){
    #pragma unroll
    for (int j=0;j<NI;j++){
      #pragma unroll
      for (int t=0;t<4;t++){
        int m = rowbase + i*16 + t;
        int n = colbase + j*16;
        float v = acc[i][j][t];
        if (EPI==1){ v += bias[n]; v = (v > 20.f) ? v : log1pf(expf(v)); }
        if (EPI==2){ v += res[(size_t)m*ldc + n]; }
        C[(size_t)m*ldc + n] = v;
      }
    }
  }
}

// -------- depthwise causal conv(4) + SiLU; reads x-half of xz, writes bf16 --------
__global__ __launch_bounds__(256) void k_conv(const float* __restrict__ xz, const float* __restrict__ cw,
                                              const float* __restrict__ cb, u16* __restrict__ xc){
  int idx = blockIdx.x*256 + threadIdx.x;   // NROWS*ED
  int e   = idx & (ED-1);
  int row = idx >> 11;
  int l   = row & (LEN-1);
  float acc = cb[e];
  #pragma unroll
  for (int k=0;k<4;k++){
    int t = l + k - 3;
    if (t >= 0) acc += xz[(size_t)(row + k - 3)*(2*ED) + e] * cw[e*4+k];
  }
  float s = acc / (1.f + __expf(-acc));
  xc[idx] = f2bf(s);
}

// -------- chunked selective scan --------
__global__ __launch_bounds__(256) void k_scan1(const float* __restrict__ dt, const u16* __restrict__ xc,
    const float* __restrict__ xdbl, const float* __restrict__ A_log,
    float* __restrict__ P, float* __restrict__ Q)
{
  int e  = (blockIdx.x & 7)*256 + threadIdx.x;
  int ch = (blockIdx.x >> 3) & (NCH-1);
  int b  = blockIdx.x >> 8;
  float An[NST], h[NST], p[NST];
  #pragma unroll
  for (int n=0;n<NST;n++){ An[n] = -__expf(A_log[e*NST+n]); h[n]=0.f; p[n]=1.f; }
  int row0 = b*LEN + ch*CHL;
  for (int s=0;s<CHL;s++){
    int row = row0 + s;
    float dtv = dt[(size_t)row*ED + e];
    float xv  = bf2f(xc[(size_t)row*ED + e]);
    float dx  = dtv*xv;
    const float* bp = xdbl + (size_t)row*XDBL + DTR;
    #pragma unroll
    for (int n=0;n<NST;n++){
      float dA = __expf(dtv*An[n]);
      p[n] *= dA;
      h[n] = dA*h[n] + dx*bp[n];
    }
  }
  size_t o = ((size_t)(b*NCH + ch)*ED + e)*NST;
  #pragma unroll
  for (int n=0;n<NST;n++){ P[o+n]=p[n]; Q[o+n]=h[n]; }
}

__global__ __launch_bounds__(256) void k_scan2(const float* __restrict__ P, const float* __restrict__ Q,
                                               float* __restrict__ H){
  int idx = blockIdx.x*256 + threadIdx.x;   // NB*ED*NST = 65536
  int n = idx & (NST-1);
  int e = (idx >> 4) & (ED-1);
  int b = idx >> 15;
  float h = 0.f;
  for (int c=0;c<NCH;c++){
    size_t o = ((size_t)(b*NCH + c)*ED + e)*NST + n;
    H[o] = h;
    h = P[o]*h + Q[o];
  }
}

__global__ __launch_bounds__(256) void k_scan3(const float* __restrict__ dt, const u16* __restrict__ xc,
    const float* __restrict__ xdbl, const float* __restrict__ A_log, const float* __restrict__ H,
    float* __restrict__ ys)
{
  int e  = (blockIdx.x & 7)*256 + threadIdx.x;
  int ch = (blockIdx.x >> 3) & (NCH-1);
  int b  = blockIdx.x >> 8;
  float An[NST], h[NST];
  size_t o = ((size_t)(b*NCH + ch)*ED + e)*NST;
  #pragma unroll
  for (int n=0;n<NST;n++){ An[n] = -__expf(A_log[e*NST+n]); h[n]=H[o+n]; }
  int row0 = b*LEN + ch*CHL;
  for (int s=0;s<CHL;s++){
    int row = row0 + s;
    float dtv = dt[(size_t)row*ED + e];
    float xv  = bf2f(xc[(size_t)row*ED + e]);
    float dx  = dtv*xv;
    const float* bp = xdbl + (size_t)row*XDBL + DTR;
    const float* cp = bp + NST;
    float y = 0.f;
    #pragma unroll
    for (int n=0;n<NST;n++){
      float dA = __expf(dtv*An[n]);
      h[n] = dA*h[n] + dx*bp[n];
      y += h[n]*cp[n];
    }
    ys[(size_t)row*ED + e] = y;
  }
}

// -------- y = (ys + x*D) * silu(z), write bf16 --------
__global__ __launch_bounds__(256) void k_yz(const float* __restrict__ ys, const u16* __restrict__ xc,
    const float* __restrict__ Dp, const float* __restrict__ xz, u16* __restrict__ yb){
  int idx = blockIdx.x*256 + threadIdx.x;
  int e   = idx & (ED-1);
  int row = idx >> 11;
  float y = ys[idx] + bf2f(xc[idx]) * Dp[e];
  float z = xz[(size_t)row*(2*ED) + ED + e];
  float sz = z / (1.f + __expf(-z));
  yb[idx] = f2bf(y*sz);
}

extern "C" void kernel_launch(void* const* d_in, const int* in_sizes, int n_in,
                              void* d_out, int out_size, void* d_ws, size_t ws_size,
                              hipStream_t stream) {
  const float* hid    = (const float*)d_in[0];
  const float* ln_w   = (const float*)d_in[1];
  const float* ln_b   = (const float*)d_in[2];
  const float* w_in   = (const float*)d_in[3];
  const float* conv_w = (const float*)d_in[4];
  const float* conv_b = (const float*)d_in[5];
  const float* w_xp   = (const float*)d_in[6];
  const float* w_dt   = (const float*)d_in[7];
  const float* dt_b   = (const float*)d_in[8];
  const float* A_log  = (const float*)d_in[9];
  const float* Dp     = (const float*)d_in[10];
  const float* w_op   = (const float*)d_in[11];
  float* out = (float*)d_out;

  char* p = (char*)d_ws;
  auto alloc = [&](size_t bytes)->char* {
    char* q = p; p += (bytes + 255) & ~(size_t)255; return q;
  };
  u16*   w_in_b = (u16*)  alloc((size_t)4096*1024*2);
  u16*   w_xp_b = (u16*)  alloc((size_t)96*2048*2);
  u16*   w_dt_b = (u16*)  alloc((size_t)2048*64*2);
  u16*   w_op_b = (u16*)  alloc((size_t)1024*2048*2);
  u16*   h_ln   = (u16*)  alloc((size_t)NROWS*DM*2);
  float* xz     = (float*)alloc((size_t)NROWS*2*ED*4);
  u16*   xc     = (u16*)  alloc((size_t)NROWS*ED*2);
  float* xdbl   = (float*)alloc((size_t)NROWS*XDBL*4);
  u16*   xdbl_b = (u16*)  alloc((size_t)NROWS*XDBL*2);
  float* dtf    = (float*)alloc((size_t)NROWS*ED*4);
  float* P      = (float*)alloc((size_t)NB*NCH*ED*NST*4);
  float* Q      = (float*)alloc((size_t)NB*NCH*ED*NST*4);
  float* H      = (float*)alloc((size_t)NB*NCH*ED*NST*4);
  float* ys     = (float*)alloc((size_t)NROWS*ED*4);
  u16*   yb     = (u16*)  alloc((size_t)NROWS*ED*2);

  // weight + activation converts
  k_f2bf<<<(4096*1024+255)/256,256,0,stream>>>(w_in, w_in_b, 4096*1024);
  k_f2bf<<<(96*2048+255)/256,256,0,stream>>>(w_xp, w_xp_b, 96*2048);
  k_f2bf<<<(2048*64+255)/256,256,0,stream>>>(w_dt, w_dt_b, 2048*64);
  k_f2bf<<<(1024*2048+255)/256,256,0,stream>>>(w_op, w_op_b, 1024*2048);

  k_ln<<<NROWS,256,0,stream>>>(hid, ln_w, ln_b, h_ln);

  dim3 g1(4096/128, 4096/128);
  k_gemm_bt<4,4,2,2,0><<<g1,256,0,stream>>>(h_ln, w_in_b, xz, 4096,4096,1024, 1024,1024,4096, nullptr,nullptr);

  k_conv<<<NROWS*ED/256,256,0,stream>>>(xz, conv_w, conv_b, xc);

  dim3 g2(4096/64, 1);
  k_gemm_bt<1,6,4,1,0><<<g2,256,0,stream>>>(xc, w_xp_b, xdbl, 4096,96,2048, 2048,2048,96, nullptr,nullptr);

  k_f2bf<<<(NROWS*XDBL+255)/256,256,0,stream>>>(xdbl, xdbl_b, NROWS*XDBL);

  dim3 g3(4096/128, 2048/128);
  k_gemm_bt<4,4,2,2,1><<<g3,256,0,stream>>>(xdbl_b, w_dt_b, dtf, 4096,2048,64, 96,64,2048, dt_b, nullptr);

  k_scan1<<<512,256,0,stream>>>(dtf, xc, xdbl, A_log, P, Q);
  k_scan2<<<256,256,0,stream>>>(P, Q, H);
  k_scan3<<<512,256,0,stream>>>(dtf, xc, xdbl, A_log, H, ys);

  k_yz<<<NROWS*ED/256,256,0,stream>>>(ys, xc, Dp, xz, yb);

  dim3 g4(4096/128, 1024/128);
  k_gemm_bt<4,4,2,2,2><<<g4,256,0,stream>>>(yb, w_op_b, out, 4096,1024,2048, 2048,2048,1024, nullptr, hid);
}

// Round 2
// 399.218 us; speedup vs baseline: 1.1124x; 1.1124x over previous
//
#include <hip/hip_runtime.h>

#define DM 1024
#define ED 2048
#define LEN 2048
#define NB 2
#define NROWS (NB*LEN)   // 4096
#define DTR 64
#define NST 16
#define XDBL 96          // DTR + 2*NST
#define NCH 32
#define CHL 64           // LEN/NCH

typedef __attribute__((ext_vector_type(8))) __bf16 bf16x8;
typedef __attribute__((ext_vector_type(8))) short short8;
typedef __attribute__((ext_vector_type(4))) float f32x4;
typedef unsigned short u16;
typedef __attribute__((ext_vector_type(4))) unsigned short u16x4;

__device__ __forceinline__ u16 f2bf(float f){
  union { float f; unsigned int u; } v; v.f = f;
  unsigned int u = v.u;
  return (u16)((u + 0x7FFFu + ((u >> 16) & 1u)) >> 16);
}
__device__ __forceinline__ float bf2f(u16 h){
  union { unsigned int u; float f; } v; v.u = ((unsigned int)h) << 16; return v.f;
}

__device__ __forceinline__ void gload16(const u16* g, u16* l){
  __builtin_amdgcn_global_load_lds((const __attribute__((address_space(1))) unsigned int*)(g),
                                   (__attribute__((address_space(3))) unsigned int*)(l), 16, 0, 0);
}

__global__ __launch_bounds__(256) void k_f2bf(const float* __restrict__ in, u16* __restrict__ out, int n){
  int i = blockIdx.x*256 + threadIdx.x;
  if (i < n) out[i] = f2bf(in[i]);
}

// -------- LayerNorm: one block per row of 1024 --------
__global__ __launch_bounds__(256) void k_ln(const float* __restrict__ x, const float* __restrict__ w,
                                            const float* __restrict__ b, u16* __restrict__ out){
  int row = blockIdx.x;
  const float4* xp = reinterpret_cast<const float4*>(x + (size_t)row*DM);
  float4 v = xp[threadIdx.x];
  float s  = v.x+v.y+v.z+v.w;
  float sq = v.x*v.x+v.y*v.y+v.z*v.z+v.w*v.w;
  #pragma unroll
  for (int off=32; off; off>>=1){ s += __shfl_xor(s, off); sq += __shfl_xor(sq, off); }
  __shared__ float red[8];
  int wid = threadIdx.x>>6, lane = threadIdx.x&63;
  if (!lane){ red[wid]=s; red[4+wid]=sq; }
  __syncthreads();
  s  = red[0]+red[1]+red[2]+red[3];
  sq = red[4]+red[5]+red[6]+red[7];
  float mean = s * (1.0f/DM);
  float var  = sq * (1.0f/DM) - mean*mean;
  float rstd = rsqrtf(var + 1e-5f);
  int c0 = threadIdx.x*4;
  float vals[4] = {v.x,v.y,v.z,v.w};
  u16x4 o;
  #pragma unroll
  for (int j=0;j<4;j++){
    int c = c0+j;
    o[j] = f2bf((vals[j]-mean)*rstd*w[c] + b[c]);
  }
  *reinterpret_cast<u16x4*>(out + (size_t)row*DM + c0) = o;
}

// -------- m97-style LDS-staged GEMM: C[M,N] = A[M,K]*B[N,K]^T --------
// 128x128 tile, 4 waves (2x2), BK=32, global_load_lds w=16.
// EPI: 0 plain, 1 softplus(acc+bias[n]), 2 acc+res[m*ldc+n]. OUTBF: write bf16.
template<int EPI, int OUTBF>
__global__ __launch_bounds__(256) void k_gemm128(
    const u16* __restrict__ A, const u16* __restrict__ B,
    void* __restrict__ Cv, int K, int lda, int ldb, int ldc,
    const float* __restrict__ bias, const float* __restrict__ res)
{
  __shared__ u16 As[128*32];
  __shared__ u16 Bs[128*32];
  int t    = threadIdx.x;
  int lane = t & 63;
  int w    = t >> 6;
  int wm = w & 1, wn = w >> 1;
  int bm = blockIdx.x * 128, bn = blockIdx.y * 128;
  int r  = lane & 15;
  int ks = (lane >> 4) * 8;

  // staging: thread t covers 16B at LDS byte offset t*16 (rows 0..63), +64 rows second half
  int srow = t >> 2;
  int scol = (t & 3) * 8;
  const u16* Ag0 = A + (size_t)(bm + srow)*lda + scol;
  const u16* Ag1 = A + (size_t)(bm + 64 + srow)*lda + scol;
  const u16* Bg0 = B + (size_t)(bn + srow)*ldb + scol;
  const u16* Bg1 = B + (size_t)(bn + 64 + srow)*ldb + scol;
  u16* Al0 = As + t*8;
  u16* Al1 = As + 64*32 + t*8;
  u16* Bl0 = Bs + t*8;
  u16* Bl1 = Bs + 64*32 + t*8;

  f32x4 acc[4][4];
  #pragma unroll
  for (int i=0;i<4;i++)
    #pragma unroll
    for (int j=0;j<4;j++) acc[i][j] = (f32x4)0.f;

  const u16* Ar = As + (size_t)(wm*64 + r)*32 + ks;
  const u16* Br = Bs + (size_t)(wn*64 + r)*32 + ks;

  for (int kk=0; kk<K; kk+=32){
    gload16(Ag0 + kk, Al0);
    gload16(Ag1 + kk, Al1);
    gload16(Bg0 + kk, Bl0);
    gload16(Bg1 + kk, Bl1);
    __syncthreads();
    short8 a[4], b[4];
    #pragma unroll
    for (int i=0;i<4;i++) a[i] = *reinterpret_cast<const short8*>(Ar + i*16*32);
    #pragma unroll
    for (int j=0;j<4;j++) b[j] = *reinterpret_cast<const short8*>(Br + j*16*32);
    #pragma unroll
    for (int i=0;i<4;i++)
      #pragma unroll
      for (int j=0;j<4;j++)
        acc[i][j] = __builtin_amdgcn_mfma_f32_16x16x32_bf16(
            __builtin_bit_cast(bf16x8, a[i]), __builtin_bit_cast(bf16x8, b[j]), acc[i][j], 0,0,0);
    __syncthreads();
  }

  int rowbase = bm + wm*64 + (lane>>4)*4;
  int colbase = bn + wn*64 + (lane&15);
  float* Cf = (float*)Cv;
  u16*   Cb = (u16*)Cv;
  #pragma unroll
  for (int i=0;i<4;i++){
    #pragma unroll
    for (int j=0;j<4;j++){
      #pragma unroll
      for (int tt=0;tt<4;tt++){
        int m = rowbase + i*16 + tt;
        int n = colbase + j*16;
        float v = acc[i][j][tt];
        if (EPI==1){ v += bias[n]; v = (v > 20.f) ? v : log1pf(expf(v)); }
        if (EPI==2){ v += res[(size_t)m*ldc + n]; }
        if (OUTBF) Cb[(size_t)m*ldc + n] = f2bf(v);
        else       Cf[(size_t)m*ldc + n] = v;
      }
    }
  }
}

// -------- small-N direct GEMM (x_proj): one wave per 16 rows, NI=6 (N=96) --------
__global__ __launch_bounds__(64) void k_gemm_xp(
    const u16* __restrict__ A, const u16* __restrict__ B,
    u16* __restrict__ C, int K, int lda, int ldb, int ldc)
{
  int lane = threadIdx.x;
  int bm = blockIdx.x * 16;
  int r  = lane & 15;
  int ks = (lane >> 4) * 8;
  const u16* Ap = A + (size_t)(bm + r)*lda + ks;
  const u16* Bp = B + (size_t)r*ldb + ks;
  f32x4 acc[6];
  #pragma unroll
  for (int j=0;j<6;j++) acc[j] = (f32x4)0.f;
  for (int kk=0; kk<K; kk+=32){
    short8 a = *reinterpret_cast<const short8*>(Ap + kk);
    #pragma unroll
    for (int j=0;j<6;j++){
      short8 b = *reinterpret_cast<const short8*>(Bp + (size_t)j*16*ldb + kk);
      acc[j] = __builtin_amdgcn_mfma_f32_16x16x32_bf16(
          __builtin_bit_cast(bf16x8, a), __builtin_bit_cast(bf16x8, b), acc[j], 0,0,0);
    }
  }
  int rowbase = bm + (lane>>4)*4;
  int colbase = lane & 15;
  #pragma unroll
  for (int j=0;j<6;j++)
    #pragma unroll
    for (int tt=0;tt<4;tt++)
      C[(size_t)(rowbase+tt)*ldc + colbase + j*16] = f2bf(acc[j][tt]);
}

// -------- depthwise causal conv(4) + SiLU; reads bf16 x-half of xz, writes bf16 --------
__global__ __launch_bounds__(256) void k_conv(const u16* __restrict__ xz, const float* __restrict__ cw,
                                              const float* __restrict__ cb, u16* __restrict__ xc){
  int idx = blockIdx.x*256 + threadIdx.x;   // NROWS*ED
  int e   = idx & (ED-1);
  int row = idx >> 11;
  int l   = row & (LEN-1);
  float acc = cb[e];
  #pragma unroll
  for (int k=0;k<4;k++){
    int t = l + k - 3;
    if (t >= 0) acc += bf2f(xz[(size_t)(row + k - 3)*(2*ED) + e]) * cw[e*4+k];
  }
  float s = acc / (1.f + __expf(-acc));
  xc[idx] = f2bf(s);
}

// -------- chunked selective scan --------
__global__ __launch_bounds__(256) void k_scan1(const float* __restrict__ dt, const u16* __restrict__ xc,
    const u16* __restrict__ xdb, const float* __restrict__ A_log,
    float* __restrict__ P, float* __restrict__ Q)
{
  int e  = (blockIdx.x & 7)*256 + threadIdx.x;
  int ch = (blockIdx.x >> 3) & (NCH-1);
  int b  = blockIdx.x >> 8;
  float An[NST], h[NST], p[NST];
  #pragma unroll
  for (int n=0;n<NST;n++){ An[n] = -__expf(A_log[e*NST+n]) * 1.44269504f; h[n]=0.f; p[n]=1.f; }
  int row0 = b*LEN + ch*CHL;
  for (int s=0;s<CHL;s++){
    int row = row0 + s;
    float dtv = dt[(size_t)row*ED + e];
    float xv  = bf2f(xc[(size_t)row*ED + e]);
    float dx  = dtv*xv;
    short8 bv0 = *reinterpret_cast<const short8*>(xdb + (size_t)row*XDBL + DTR);
    short8 bv1 = *reinterpret_cast<const short8*>(xdb + (size_t)row*XDBL + DTR + 8);
    float bf[NST];
    #pragma unroll
    for (int n=0;n<8;n++){ bf[n] = bf2f((u16)bv0[n]); bf[n+8] = bf2f((u16)bv1[n]); }
    #pragma unroll
    for (int n=0;n<NST;n++){
      float dA = exp2f(dtv*An[n]);
      p[n] *= dA;
      h[n] = dA*h[n] + dx*bf[n];
    }
  }
  size_t o = ((size_t)(b*NCH + ch)*ED + e)*NST;
  #pragma unroll
  for (int n=0;n<NST;n++){ P[o+n]=p[n]; Q[o+n]=h[n]; }
}

__global__ __launch_bounds__(256) void k_scan2(const float* __restrict__ P, const float* __restrict__ Q,
                                               float* __restrict__ H){
  int idx = blockIdx.x*256 + threadIdx.x;   // NB*ED*NST = 65536
  int n = idx & (NST-1);
  int e = (idx >> 4) & (ED-1);
  int b = idx >> 15;
  float h = 0.f;
  for (int c=0;c<NCH;c++){
    size_t o = ((size_t)(b*NCH + c)*ED + e)*NST + n;
    H[o] = h;
    h = P[o]*h + Q[o];
  }
}

// scan replay + y = (ys + x*D)*silu(z), writes bf16 yb
__global__ __launch_bounds__(256) void k_scan3(const float* __restrict__ dt, const u16* __restrict__ xc,
    const u16* __restrict__ xdb, const float* __restrict__ A_log, const float* __restrict__ H,
    const float* __restrict__ Dp, const u16* __restrict__ xz, u16* __restrict__ yb)
{
  int e  = (blockIdx.x & 7)*256 + threadIdx.x;
  int ch = (blockIdx.x >> 3) & (NCH-1);
  int b  = blockIdx.x >> 8;
  float An[NST], h[NST];
  size_t o = ((size_t)(b*NCH + ch)*ED + e)*NST;
  #pragma unroll
  for (int n=0;n<NST;n++){ An[n] = -__expf(A_log[e*NST+n]) * 1.44269504f; h[n]=H[o+n]; }
  float dpe = Dp[e];
  int row0 = b*LEN + ch*CHL;
  for (int s=0;s<CHL;s++){
    int row = row0 + s;
    float dtv = dt[(size_t)row*ED + e];
    float xv  = bf2f(xc[(size_t)row*ED + e]);
    float dx  = dtv*xv;
    short8 bv0 = *reinterpret_cast<const short8*>(xdb + (size_t)row*XDBL + DTR);
    short8 bv1 = *reinterpret_cast<const short8*>(xdb + (size_t)row*XDBL + DTR + 8);
    short8 cv0 = *reinterpret_cast<const short8*>(xdb + (size_t)row*XDBL + DTR + NST);
    short8 cv1 = *reinterpret_cast<const short8*>(xdb + (size_t)row*XDBL + DTR + NST + 8);
    float bf[NST], cf[NST];
    #pragma unroll
    for (int n=0;n<8;n++){
      bf[n] = bf2f((u16)bv0[n]); bf[n+8] = bf2f((u16)bv1[n]);
      cf[n] = bf2f((u16)cv0[n]); cf[n+8] = bf2f((u16)cv1[n]);
    }
    float y = 0.f;
    #pragma unroll
    for (int n=0;n<NST;n++){
      float dA = exp2f(dtv*An[n]);
      h[n] = dA*h[n] + dx*bf[n];
      y += h[n]*cf[n];
    }
    float ytot = y + xv*dpe;
    float z = bf2f(xz[(size_t)row*(2*ED) + ED + e]);
    float sz = z / (1.f + __expf(-z));
    yb[(size_t)row*ED + e] = f2bf(ytot*sz);
  }
}

extern "C" void kernel_launch(void* const* d_in, const int* in_sizes, int n_in,
                              void* d_out, int out_size, void* d_ws, size_t ws_size,
                              hipStream_t stream) {
  const float* hid    = (const float*)d_in[0];
  const float* ln_w   = (const float*)d_in[1];
  const float* ln_b   = (const float*)d_in[2];
  const float* w_in   = (const float*)d_in[3];
  const float* conv_w = (const float*)d_in[4];
  const float* conv_b = (const float*)d_in[5];
  const float* w_xp   = (const float*)d_in[6];
  const float* w_dt   = (const float*)d_in[7];
  const float* dt_b   = (const float*)d_in[8];
  const float* A_log  = (const float*)d_in[9];
  const float* Dp     = (const float*)d_in[10];
  const float* w_op   = (const float*)d_in[11];
  float* out = (float*)d_out;

  char* p = (char*)d_ws;
  auto alloc = [&](size_t bytes)->char* {
    char* q = p; p += (bytes + 255) & ~(size_t)255; return q;
  };
  u16*   w_in_b = (u16*)  alloc((size_t)4096*1024*2);
  u16*   w_xp_b = (u16*)  alloc((size_t)96*2048*2);
  u16*   w_dt_b = (u16*)  alloc((size_t)2048*64*2);
  u16*   w_op_b = (u16*)  alloc((size_t)1024*2048*2);
  u16*   h_ln   = (u16*)  alloc((size_t)NROWS*DM*2);
  u16*   xz     = (u16*)  alloc((size_t)NROWS*2*ED*2);
  u16*   xc     = (u16*)  alloc((size_t)NROWS*ED*2);
  u16*   xdbl_b = (u16*)  alloc((size_t)NROWS*XDBL*2);
  float* dtf    = (float*)alloc((size_t)NROWS*ED*4);
  float* P      = (float*)alloc((size_t)NB*NCH*ED*NST*4);
  float* Q      = (float*)alloc((size_t)NB*NCH*ED*NST*4);
  float* H      = (float*)alloc((size_t)NB*NCH*ED*NST*4);
  u16*   yb     = (u16*)  alloc((size_t)NROWS*ED*2);

  // weight converts
  k_f2bf<<<(4096*1024+255)/256,256,0,stream>>>(w_in, w_in_b, 4096*1024);
  k_f2bf<<<(96*2048+255)/256,256,0,stream>>>(w_xp, w_xp_b, 96*2048);
  k_f2bf<<<(2048*64+255)/256,256,0,stream>>>(w_dt, w_dt_b, 2048*64);
  k_f2bf<<<(1024*2048+255)/256,256,0,stream>>>(w_op, w_op_b, 1024*2048);

  k_ln<<<NROWS,256,0,stream>>>(hid, ln_w, ln_b, h_ln);

  // in_proj: 4096x4096x1024, bf16 out
  dim3 g1(4096/128, 4096/128);
  k_gemm128<0,1><<<g1,256,0,stream>>>(h_ln, w_in_b, xz, 1024, 1024, 1024, 4096, nullptr, nullptr);

  k_conv<<<NROWS*ED/256,256,0,stream>>>(xz, conv_w, conv_b, xc);

  // x_proj: 4096x96x2048, bf16 out
  k_gemm_xp<<<4096/16,64,0,stream>>>(xc, w_xp_b, xdbl_b, 2048, 2048, 2048, 96);

  // dt_proj: 4096x2048x64, softplus+bias, f32 out
  dim3 g3(4096/128, 2048/128);
  k_gemm128<1,0><<<g3,256,0,stream>>>(xdbl_b, w_dt_b, dtf, 64, 96, 64, 2048, dt_b, nullptr);

  k_scan1<<<512,256,0,stream>>>(dtf, xc, xdbl_b, A_log, P, Q);
  k_scan2<<<256,256,0,stream>>>(P, Q, H);
  k_scan3<<<512,256,0,stream>>>(dtf, xc, xdbl_b, A_log, H, Dp, xz, yb);

  // out_proj: 4096x1024x2048, +residual, f32 out
  dim3 g4(4096/128, 1024/128);
  k_gemm128<2,0><<<g4,256,0,stream>>>(yb, w_op_b, out, 2048, 2048, 2048, 1024, nullptr, hid);
}

// Round 3
// 296.889 us; speedup vs baseline: 1.4958x; 1.3447x over previous
//
#include <hip/hip_runtime.h>

#define DM 1024
#define ED 2048
#define LEN 2048
#define NB 2
#define NROWS (NB*LEN)   // 4096
#define DTR 64
#define NST 16
#define XDBL 96          // DTR + 2*NST
#define NCH 32
#define CHL 64           // LEN/NCH

typedef __attribute__((ext_vector_type(8))) __bf16 bf16x8;
typedef __attribute__((ext_vector_type(8))) short short8;
typedef __attribute__((ext_vector_type(4))) float f32x4;
typedef unsigned short u16;
typedef __attribute__((ext_vector_type(4))) unsigned short u16x4;

__device__ __forceinline__ u16 f2bf(float f){
  union { float f; unsigned int u; } v; v.f = f;
  unsigned int u = v.u;
  return (u16)((u + 0x7FFFu + ((u >> 16) & 1u)) >> 16);
}
__device__ __forceinline__ float bf2f(u16 h){
  union { unsigned int u; float f; } v; v.u = ((unsigned int)h) << 16; return v.f;
}

__device__ __forceinline__ void gload16(const u16* g, u16* l){
  __builtin_amdgcn_global_load_lds((const __attribute__((address_space(1))) unsigned int*)(g),
                                   (__attribute__((address_space(3))) unsigned int*)(l), 16, 0, 0);
}

// -------- fused weight converts (4 arrays, vec4) --------
__global__ __launch_bounds__(256) void k_cvt_all(
    const float* __restrict__ w0, const float* __restrict__ w1,
    const float* __restrict__ w2, const float* __restrict__ w3,
    u16* __restrict__ o0, u16* __restrict__ o1, u16* __restrict__ o2, u16* __restrict__ o3){
  int i = blockIdx.x*256 + threadIdx.x;   // vec4 index
  const int n0 = 4194304/4, n1 = 196608/4, n2 = 131072/4, n3 = 2097152/4;
  const float* src; u16* dst; int off;
  if (i < n0){ src=w0; dst=o0; off=i; }
  else if (i < n0+n1){ src=w1; dst=o1; off=i-n0; }
  else if (i < n0+n1+n2){ src=w2; dst=o2; off=i-n0-n1; }
  else if (i < n0+n1+n2+n3){ src=w3; dst=o3; off=i-n0-n1-n2; }
  else return;
  float4 v = reinterpret_cast<const float4*>(src)[off];
  u16x4 o; o[0]=f2bf(v.x); o[1]=f2bf(v.y); o[2]=f2bf(v.z); o[3]=f2bf(v.w);
  reinterpret_cast<u16x4*>(dst)[off] = o;
}

// -------- LayerNorm: one block per row of 1024 --------
__global__ __launch_bounds__(256) void k_ln(const float* __restrict__ x, const float* __restrict__ w,
                                            const float* __restrict__ b, u16* __restrict__ out){
  int row = blockIdx.x;
  const float4* xp = reinterpret_cast<const float4*>(x + (size_t)row*DM);
  float4 v = xp[threadIdx.x];
  float s  = v.x+v.y+v.z+v.w;
  float sq = v.x*v.x+v.y*v.y+v.z*v.z+v.w*v.w;
  #pragma unroll
  for (int off=32; off; off>>=1){ s += __shfl_xor(s, off); sq += __shfl_xor(sq, off); }
  __shared__ float red[8];
  int wid = threadIdx.x>>6, lane = threadIdx.x&63;
  if (!lane){ red[wid]=s; red[4+wid]=sq; }
  __syncthreads();
  s  = red[0]+red[1]+red[2]+red[3];
  sq = red[4]+red[5]+red[6]+red[7];
  float mean = s * (1.0f/DM);
  float var  = sq * (1.0f/DM) - mean*mean;
  float rstd = rsqrtf(var + 1e-5f);
  int c0 = threadIdx.x*4;
  float vals[4] = {v.x,v.y,v.z,v.w};
  u16x4 o;
  #pragma unroll
  for (int j=0;j<4;j++){
    int c = c0+j;
    o[j] = f2bf((vals[j]-mean)*rstd*w[c] + b[c]);
  }
  *reinterpret_cast<u16x4*>(out + (size_t)row*DM + c0) = o;
}

// -------- m97-style LDS-staged GEMM: C[M,N] = A[M,K]*B[N,K]^T --------
// 128x128 tile, 4 waves (2x2), BK=32, global_load_lds w=16.
// EPI: 0 plain, 1 softplus(acc+bias[n]), 2 acc+res[m*ldc+n]. OUTBF: write bf16.
template<int EPI, int OUTBF>
__global__ __launch_bounds__(256) void k_gemm128(
    const u16* __restrict__ A, const u16* __restrict__ B,
    void* __restrict__ Cv, int K, int lda, int ldb, int ldc,
    const float* __restrict__ bias, const float* __restrict__ res)
{
  __shared__ u16 As[128*32];
  __shared__ u16 Bs[128*32];
  int t    = threadIdx.x;
  int lane = t & 63;
  int w    = t >> 6;
  int wm = w & 1, wn = w >> 1;
  int bm = blockIdx.x * 128, bn = blockIdx.y * 128;
  int r  = lane & 15;
  int ks = (lane >> 4) * 8;

  int srow = t >> 2;
  int scol = (t & 3) * 8;
  const u16* Ag0 = A + (size_t)(bm + srow)*lda + scol;
  const u16* Ag1 = A + (size_t)(bm + 64 + srow)*lda + scol;
  const u16* Bg0 = B + (size_t)(bn + srow)*ldb + scol;
  const u16* Bg1 = B + (size_t)(bn + 64 + srow)*ldb + scol;
  u16* Al0 = As + t*8;
  u16* Al1 = As + 64*32 + t*8;
  u16* Bl0 = Bs + t*8;
  u16* Bl1 = Bs + 64*32 + t*8;

  f32x4 acc[4][4];
  #pragma unroll
  for (int i=0;i<4;i++)
    #pragma unroll
    for (int j=0;j<4;j++) acc[i][j] = (f32x4)0.f;

  const u16* Ar = As + (size_t)(wm*64 + r)*32 + ks;
  const u16* Br = Bs + (size_t)(wn*64 + r)*32 + ks;

  for (int kk=0; kk<K; kk+=32){
    gload16(Ag0 + kk, Al0);
    gload16(Ag1 + kk, Al1);
    gload16(Bg0 + kk, Bl0);
    gload16(Bg1 + kk, Bl1);
    __syncthreads();
    short8 a[4], b[4];
    #pragma unroll
    for (int i=0;i<4;i++) a[i] = *reinterpret_cast<const short8*>(Ar + i*16*32);
    #pragma unroll
    for (int j=0;j<4;j++) b[j] = *reinterpret_cast<const short8*>(Br + j*16*32);
    #pragma unroll
    for (int i=0;i<4;i++)
      #pragma unroll
      for (int j=0;j<4;j++)
        acc[i][j] = __builtin_amdgcn_mfma_f32_16x16x32_bf16(
            __builtin_bit_cast(bf16x8, a[i]), __builtin_bit_cast(bf16x8, b[j]), acc[i][j], 0,0,0);
    __syncthreads();
  }

  int rowbase = bm + wm*64 + (lane>>4)*4;
  int colbase = bn + wn*64 + (lane&15);
  float* Cf = (float*)Cv;
  u16*   Cb = (u16*)Cv;
  #pragma unroll
  for (int i=0;i<4;i++){
    #pragma unroll
    for (int j=0;j<4;j++){
      #pragma unroll
      for (int tt=0;tt<4;tt++){
        int m = rowbase + i*16 + tt;
        int n = colbase + j*16;
        float v = acc[i][j][tt];
        if (EPI==1){ v += bias[n]; v = (v > 20.f) ? v : log1pf(expf(v)); }
        if (EPI==2){ v += res[(size_t)m*ldc + n]; }
        if (OUTBF) Cb[(size_t)m*ldc + n] = f2bf(v);
        else       Cf[(size_t)m*ldc + n] = v;
      }
    }
  }
}

// -------- x_proj split-K GEMM: M=4096 N=96 K=2048; 8 waves, K-slice 256 each --------
__global__ __launch_bounds__(512) void k_gemm_xp(
    const u16* __restrict__ A, const u16* __restrict__ B, u16* __restrict__ C)
{
  __shared__ float red[8][16][97];
  int t = threadIdx.x;
  int lane = t & 63;
  int w = t >> 6;                 // K-slice 0..7
  int bm = blockIdx.x * 16;
  int r  = lane & 15;
  int ks = (lane >> 4) * 8;
  int k0 = w * 256;
  const u16* Ap = A + (size_t)(bm + r)*2048 + k0 + ks;
  const u16* Bp = B + (size_t)r*2048 + k0 + ks;
  f32x4 acc[6];
  #pragma unroll
  for (int j=0;j<6;j++) acc[j] = (f32x4)0.f;
  #pragma unroll
  for (int kk=0; kk<256; kk+=32){
    short8 a = *reinterpret_cast<const short8*>(Ap + kk);
    #pragma unroll
    for (int j=0;j<6;j++){
      short8 b = *reinterpret_cast<const short8*>(Bp + (size_t)j*16*2048 + kk);
      acc[j] = __builtin_amdgcn_mfma_f32_16x16x32_bf16(
          __builtin_bit_cast(bf16x8, a), __builtin_bit_cast(bf16x8, b), acc[j], 0,0,0);
    }
  }
  #pragma unroll
  for (int j=0;j<6;j++)
    #pragma unroll
    for (int tt=0;tt<4;tt++)
      red[w][(lane>>4)*4+tt][(lane&15)+j*16] = acc[j][tt];
  __syncthreads();
  for (int o = t; o < 1536; o += 512){
    int rr = o / 96, cc = o % 96;
    float s = 0.f;
    #pragma unroll
    for (int ww=0; ww<8; ww++) s += red[ww][rr][cc];
    C[(size_t)(bm+rr)*96 + cc] = f2bf(s);
  }
}

// -------- depthwise causal conv(4) + SiLU; 8 outputs along l per thread --------
__global__ __launch_bounds__(256) void k_conv(const u16* __restrict__ xz, const float* __restrict__ cw,
                                              const float* __restrict__ cb, u16* __restrict__ xc){
  int g = blockIdx.x*256 + threadIdx.x;    // 1,048,576 threads
  int e  = g & (ED-1);
  int lg = g >> 11;                        // 0..511
  int b  = lg >> 8;
  int l0 = (lg & 255) * 8;
  int row0 = b*LEN + l0;
  float w0=cw[e*4], w1=cw[e*4+1], w2=cw[e*4+2], w3=cw[e*4+3];
  float cbe = cb[e];
  float xv[11];
  #pragma unroll
  for (int i=0;i<11;i++){
    int l = l0 + i - 3;
    xv[i] = (l>=0) ? bf2f(xz[(size_t)(row0 + i - 3)*(2*ED) + e]) : 0.f;
  }
  #pragma unroll
  for (int s=0;s<8;s++){
    float acc = cbe + xv[s]*w0 + xv[s+1]*w1 + xv[s+2]*w2 + xv[s+3]*w3;
    float sv = acc / (1.f + __expf(-acc));
    xc[(size_t)(row0+s)*ED + e] = f2bf(sv);
  }
}

// -------- chunked selective scan --------
__global__ __launch_bounds__(256) void k_scan1(const u16* __restrict__ dt, const u16* __restrict__ xc,
    const u16* __restrict__ xdb, const float* __restrict__ A_log,
    float* __restrict__ P, float* __restrict__ Q)
{
  int e  = (blockIdx.x & 7)*256 + threadIdx.x;
  int ch = (blockIdx.x >> 3) & (NCH-1);
  int b  = blockIdx.x >> 8;
  float An[NST], h[NST], p[NST];
  #pragma unroll
  for (int n=0;n<NST;n++){ An[n] = -__expf(A_log[e*NST+n]) * 1.44269504f; h[n]=0.f; p[n]=1.f; }
  int row0 = b*LEN + ch*CHL;
  for (int s=0;s<CHL;s++){
    int row = row0 + s;
    float dtv = bf2f(dt[(size_t)row*ED + e]);
    float xv  = bf2f(xc[(size_t)row*ED + e]);
    float dx  = dtv*xv;
    short8 bv0 = *reinterpret_cast<const short8*>(xdb + (size_t)row*XDBL + DTR);
    short8 bv1 = *reinterpret_cast<const short8*>(xdb + (size_t)row*XDBL + DTR + 8);
    float bf[NST];
    #pragma unroll
    for (int n=0;n<8;n++){ bf[n] = bf2f((u16)bv0[n]); bf[n+8] = bf2f((u16)bv1[n]); }
    #pragma unroll
    for (int n=0;n<NST;n++){
      float dA = exp2f(dtv*An[n]);
      p[n] *= dA;
      h[n] = dA*h[n] + dx*bf[n];
    }
  }
  size_t o = ((size_t)(b*NCH + ch)*ED + e)*NST;
  #pragma unroll
  for (int n=0;n<NST;n++){ P[o+n]=p[n]; Q[o+n]=h[n]; }
}

__global__ __launch_bounds__(256) void k_scan2(const float* __restrict__ P, const float* __restrict__ Q,
                                               float* __restrict__ H){
  int idx = blockIdx.x*256 + threadIdx.x;   // NB*ED*NST = 65536
  int n = idx & (NST-1);
  int e = (idx >> 4) & (ED-1);
  int b = idx >> 15;
  float h = 0.f;
  for (int c=0;c<NCH;c++){
    size_t o = ((size_t)(b*NCH + c)*ED + e)*NST + n;
    H[o] = h;
    h = P[o]*h + Q[o];
  }
}

// scan replay + y = (ys + x*D)*silu(z), writes bf16 yb
__global__ __launch_bounds__(256) void k_scan3(const u16* __restrict__ dt, const u16* __restrict__ xc,
    const u16* __restrict__ xdb, const float* __restrict__ A_log, const float* __restrict__ H,
    const float* __restrict__ Dp, const u16* __restrict__ xz, u16* __restrict__ yb)
{
  int e  = (blockIdx.x & 7)*256 + threadIdx.x;
  int ch = (blockIdx.x >> 3) & (NCH-1);
  int b  = blockIdx.x >> 8;
  float An[NST], h[NST];
  size_t o = ((size_t)(b*NCH + ch)*ED + e)*NST;
  #pragma unroll
  for (int n=0;n<NST;n++){ An[n] = -__expf(A_log[e*NST+n]) * 1.44269504f; h[n]=H[o+n]; }
  float dpe = Dp[e];
  int row0 = b*LEN + ch*CHL;
  for (int s=0;s<CHL;s++){
    int row = row0 + s;
    float dtv = bf2f(dt[(size_t)row*ED + e]);
    float xv  = bf2f(xc[(size_t)row*ED + e]);
    float dx  = dtv*xv;
    short8 bv0 = *reinterpret_cast<const short8*>(xdb + (size_t)row*XDBL + DTR);
    short8 bv1 = *reinterpret_cast<const short8*>(xdb + (size_t)row*XDBL + DTR + 8);
    short8 cv0 = *reinterpret_cast<const short8*>(xdb + (size_t)row*XDBL + DTR + NST);
    short8 cv1 = *reinterpret_cast<const short8*>(xdb + (size_t)row*XDBL + DTR + NST + 8);
    float bf[NST], cf[NST];
    #pragma unroll
    for (int n=0;n<8;n++){
      bf[n] = bf2f((u16)bv0[n]); bf[n+8] = bf2f((u16)bv1[n]);
      cf[n] = bf2f((u16)cv0[n]); cf[n+8] = bf2f((u16)cv1[n]);
    }
    float y = 0.f;
    #pragma unroll
    for (int n=0;n<NST;n++){
      float dA = exp2f(dtv*An[n]);
      h[n] = dA*h[n] + dx*bf[n];
      y += h[n]*cf[n];
    }
    float ytot = y + xv*dpe;
    float z = bf2f(xz[(size_t)row*(2*ED) + ED + e]);
    float sz = z / (1.f + __expf(-z));
    yb[(size_t)row*ED + e] = f2bf(ytot*sz);
  }
}

extern "C" void kernel_launch(void* const* d_in, const int* in_sizes, int n_in,
                              void* d_out, int out_size, void* d_ws, size_t ws_size,
                              hipStream_t stream) {
  const float* hid    = (const float*)d_in[0];
  const float* ln_w   = (const float*)d_in[1];
  const float* ln_b   = (const float*)d_in[2];
  const float* w_in   = (const float*)d_in[3];
  const float* conv_w = (const float*)d_in[4];
  const float* conv_b = (const float*)d_in[5];
  const float* w_xp   = (const float*)d_in[6];
  const float* w_dt   = (const float*)d_in[7];
  const float* dt_b   = (const float*)d_in[8];
  const float* A_log  = (const float*)d_in[9];
  const float* Dp     = (const float*)d_in[10];
  const float* w_op   = (const float*)d_in[11];
  float* out = (float*)d_out;

  char* p = (char*)d_ws;
  auto alloc = [&](size_t bytes)->char* {
    char* q = p; p += (bytes + 255) & ~(size_t)255; return q;
  };
  u16*   w_in_b = (u16*)  alloc((size_t)4096*1024*2);
  u16*   w_xp_b = (u16*)  alloc((size_t)96*2048*2);
  u16*   w_dt_b = (u16*)  alloc((size_t)2048*64*2);
  u16*   w_op_b = (u16*)  alloc((size_t)1024*2048*2);
  u16*   h_ln   = (u16*)  alloc((size_t)NROWS*DM*2);
  u16*   xz     = (u16*)  alloc((size_t)NROWS*2*ED*2);
  u16*   xc     = (u16*)  alloc((size_t)NROWS*ED*2);
  u16*   xdbl_b = (u16*)  alloc((size_t)NROWS*XDBL*2);
  u16*   dtf    = (u16*)  alloc((size_t)NROWS*ED*2);
  float* P      = (float*)alloc((size_t)NB*NCH*ED*NST*4);
  float* Q      = (float*)alloc((size_t)NB*NCH*ED*NST*4);
  float* H      = (float*)alloc((size_t)NB*NCH*ED*NST*4);
  u16*   yb     = (u16*)  alloc((size_t)NROWS*ED*2);

  // fused weight converts
  k_cvt_all<<<(1654784+255)/256,256,0,stream>>>(w_in, w_xp, w_dt, w_op,
                                                w_in_b, w_xp_b, w_dt_b, w_op_b);

  k_ln<<<NROWS,256,0,stream>>>(hid, ln_w, ln_b, h_ln);

  // in_proj: 4096x4096x1024, bf16 out
  dim3 g1(4096/128, 4096/128);
  k_gemm128<0,1><<<g1,256,0,stream>>>(h_ln, w_in_b, xz, 1024, 1024, 1024, 4096, nullptr, nullptr);

  k_conv<<<NROWS*ED/(256*8),256,0,stream>>>(xz, conv_w, conv_b, xc);

  // x_proj: 4096x96x2048, split-K, bf16 out
  k_gemm_xp<<<4096/16,512,0,stream>>>(xc, w_xp_b, xdbl_b);

  // dt_proj: 4096x2048x64, softplus+bias, bf16 out
  dim3 g3(4096/128, 2048/128);
  k_gemm128<1,1><<<g3,256,0,stream>>>(xdbl_b, w_dt_b, dtf, 64, 96, 64, 2048, dt_b, nullptr);

  k_scan1<<<512,256,0,stream>>>(dtf, xc, xdbl_b, A_log, P, Q);
  k_scan2<<<256,256,0,stream>>>(P, Q, H);
  k_scan3<<<512,256,0,stream>>>(dtf, xc, xdbl_b, A_log, H, Dp, xz, yb);

  // out_proj: 4096x1024x2048, +residual, f32 out
  dim3 g4(4096/128, 1024/128);
  k_gemm128<2,0><<<g4,256,0,stream>>>(yb, w_op_b, out, 2048, 2048, 2048, 1024, nullptr, hid);
}